// Round 1
// baseline (465.720 us; speedup 1.0000x reference)
//
#include <hip/hip_runtime.h>
#include <hip/hip_bf16.h>

// GAT layer, N=8192, DIN=256, DOUT=128.
// h = x@W+bW; e_ij = leaky_relu(s_src[i]+s_dst[j]+ba); p = adj ? exp(e) : 0
// (no max-subtraction: |e| <= ~10 unmasked, fp32-safe). out_i = (sum_j p_ij h_j)/(sum_j p_ij).
//
// R8: fuse build_mask into gat_attn. The standalone mask pass streamed 268 MB
// of adj at ~45us with zero compute while gat_attn ran ~120us at ~2% HBM BW.
// Each wave-lane now reads its own adj[i, j0..j0+7] span (2x dwordx4,
// 16B-aligned, paired loads fill whole 128B lines) inside the t-loop -- the
// compulsory 268 MB read hides under the VALU/MFMA work (needs only
// ~2.2 TB/s). adj is loaded NON-TEMPORAL so the stream doesn't evict the hot
// 2 MB hbB frag-tile from each XCD's 4 MB L2 (R7's reason for running
// build_mask first); num epilogue stores are non-temporal for the same
// reason (64 MB consumed only by gat_combine, from HBM either way).
// Also deletes the 8 MB mask write + 8 MB mask read and one launch.

#define NN 8192
#define DIN 256
#define DOUT 128
#define LOG2E 1.4426950408889634f

typedef __attribute__((ext_vector_type(8))) short short8;   // 8 bf16 = 4 VGPRs (MFMA A/B frag)
typedef __attribute__((ext_vector_type(4))) float floatx4;  // MFMA C/D frag
typedef __attribute__((ext_vector_type(4))) unsigned int uintx4;

// ---------------- kernel 0: W [256][128] fp32 -> WT [128][256] bf16 ----------------
__global__ void prep_wt(const float* __restrict__ W, __hip_bfloat16* __restrict__ WT) {
    int e = blockIdx.x * blockDim.x + threadIdx.x;
    if (e < DIN * DOUT) {
        int k = e >> 7;
        int d = e & 127;
        WT[d * DIN + k] = __float2bfloat16(W[e]);
    }
}

// ---------------- kernel 1: h = x@W + bW (MFMA), fused s_src/s_dst; h -> hbB frag-tile layout ----------------
// hbB flat index for h-element (row i, dim d):
//   g=i>>5, k=i&31, f=d>>4, n=d&15 -> g*4096 + f*512 + (k>>3)*128 + n*8 + (k&7)
__global__ __launch_bounds__(256, 4) void gat_h(
    const float* __restrict__ x, const __hip_bfloat16* __restrict__ WT,
    const float* __restrict__ bW, const float* __restrict__ a1, const float* __restrict__ a2,
    __hip_bfloat16* __restrict__ hbB, float* __restrict__ s_src, float* __restrict__ s_dst) {
    int tid = threadIdx.x;
    int w = tid >> 6, lane = tid & 63;
    int lm = lane & 15, lq = lane >> 4;
    int i0 = blockIdx.x * 32;
    int r0 = (w >> 1) * 16;
    int c0 = (w & 1) * 64;

    __shared__ float s1s[32], s2s[32];
    if (tid < 32) { s1s[tid] = 0.f; s2s[tid] = 0.f; }
    __syncthreads();

    floatx4 acc[4] = {};
#pragma unroll
    for (int kk = 0; kk < DIN; kk += 32) {
        const float4* xp = (const float4*)&x[(size_t)(i0 + r0 + lm) * DIN + kk + lq * 8];
        float4 xa = xp[0], xb = xp[1];
        union { short8 v; __hip_bfloat16 h[8]; } af;
        af.h[0] = __float2bfloat16(xa.x); af.h[1] = __float2bfloat16(xa.y);
        af.h[2] = __float2bfloat16(xa.z); af.h[3] = __float2bfloat16(xa.w);
        af.h[4] = __float2bfloat16(xb.x); af.h[5] = __float2bfloat16(xb.y);
        af.h[6] = __float2bfloat16(xb.z); af.h[7] = __float2bfloat16(xb.w);
#pragma unroll
        for (int t = 0; t < 4; t++) {
            int d = c0 + 16 * t + lm;
            short8 bf = *(const short8*)&WT[(size_t)d * DIN + kk + lq * 8];
            acc[t] = __builtin_amdgcn_mfma_f32_16x16x32_bf16(af.v, bf, acc[t], 0, 0, 0);
        }
    }
    float s1[4] = {0.f, 0.f, 0.f, 0.f}, s2[4] = {0.f, 0.f, 0.f, 0.f};
#pragma unroll
    for (int t = 0; t < 4; t++) {
        int d = c0 + 16 * t + lm;
        int f = (c0 >> 4) + t;
        float A1 = a1[d], A2 = a2[d], B = bW[d];
#pragma unroll
        for (int r = 0; r < 4; r++) {
            int k = r0 + lq * 4 + r;
            float h = acc[t][r] + B;
            hbB[(size_t)blockIdx.x * 4096 + f * 512 + (k >> 3) * 128 + lm * 8 + (k & 7)] =
                __float2bfloat16(h);
            s1[r] += h * A1;
            s2[r] += h * A2;
        }
    }
#pragma unroll
    for (int r = 0; r < 4; r++) {
        for (int m = 1; m < 16; m <<= 1) {
            s1[r] += __shfl_xor(s1[r], m, 64);
            s2[r] += __shfl_xor(s2[r], m, 64);
        }
    }
    if (lm == 0) {
#pragma unroll
        for (int r = 0; r < 4; r++) {
            int row = r0 + lq * 4 + r;
            atomicAdd(&s1s[row], s1[r]);
            atomicAdd(&s2s[row], s2[r]);
        }
    }
    __syncthreads();
    if (tid < 32) {
        s_src[i0 + tid] = s1s[tid] * LOG2E;   // pre-scale: exp(e) = exp2(e*log2e)
        s_dst[i0 + tid] = s2s[tid] * LOG2E;
    }
}

// adj values are int 0/1; m!=0 <=> edge present.
__device__ inline short8 make_pfrag(uintx4 m0, uintx4 m1, float ssi, float4 cd0, float4 cd1,
                                    floatx4* accd, const short8 ones) {
    float p[8];
    float e;
    e = ssi + cd0.x; e = fmaxf(e, 0.01f * e); p[0] = m0.x ? __builtin_amdgcn_exp2f(e) : 0.f;
    e = ssi + cd0.y; e = fmaxf(e, 0.01f * e); p[1] = m0.y ? __builtin_amdgcn_exp2f(e) : 0.f;
    e = ssi + cd0.z; e = fmaxf(e, 0.01f * e); p[2] = m0.z ? __builtin_amdgcn_exp2f(e) : 0.f;
    e = ssi + cd0.w; e = fmaxf(e, 0.01f * e); p[3] = m0.w ? __builtin_amdgcn_exp2f(e) : 0.f;
    e = ssi + cd1.x; e = fmaxf(e, 0.01f * e); p[4] = m1.x ? __builtin_amdgcn_exp2f(e) : 0.f;
    e = ssi + cd1.y; e = fmaxf(e, 0.01f * e); p[5] = m1.y ? __builtin_amdgcn_exp2f(e) : 0.f;
    e = ssi + cd1.z; e = fmaxf(e, 0.01f * e); p[6] = m1.z ? __builtin_amdgcn_exp2f(e) : 0.f;
    e = ssi + cd1.w; e = fmaxf(e, 0.01f * e); p[7] = m1.w ? __builtin_amdgcn_exp2f(e) : 0.f;
    union { short8 v; __hip_bfloat162 q[4]; } af;
    af.q[0] = __float22bfloat162_rn(make_float2(p[0], p[1]));
    af.q[1] = __float22bfloat162_rn(make_float2(p[2], p[3]));
    af.q[2] = __float22bfloat162_rn(make_float2(p[4], p[5]));
    af.q[3] = __float22bfloat162_rn(make_float2(p[6], p[7]));
    *accd = __builtin_amdgcn_mfma_f32_16x16x32_bf16(af.v, ones, *accd, 0, 0, 0);
    return af.v;
}

// ---------------- kernel 2: fused mask + masked softmax-weighted GEMM, 32 rows/wave ----------------
// grid = 64 row-blocks (128 rows) x JSPLIT. Wave w: rows i0=ib*128+w*32 .. +31
// as two A-frag row-groups sharing each B-frag; all 128 dims.
// Lane (lm,lq) of rowgroup rg reads adj[i0+rg*16+lm, jb0+t*32+lq*8 .. +7]
// directly (non-temporal) -- same j's as its cd0/cd1 s_dst slice.
template <int NJT>
__global__ __launch_bounds__(256, 3) void gat_attn(
    const int* __restrict__ adj, const float* __restrict__ s_src,
    const float* __restrict__ s_dst, const float* __restrict__ ba_p,
    const __hip_bfloat16* __restrict__ hbB,
    float* __restrict__ num, float* __restrict__ lpart) {
    int tid = threadIdx.x;
    int w = tid >> 6, lane = tid & 63;
    int lm = lane & 15, lq = lane >> 4;
    int b = blockIdx.x;
    int ib = b & 63;
    int jh = b >> 6;
    int i0 = ib * 128 + w * 32;
    int jb0 = jh * (NJT * 32);

    const int* arow0 = adj + (size_t)(i0 + lm) * NN + jb0 + lq * 8;
    const int* arow1 = arow0 + (size_t)16 * NN;

    float ba = ba_p[0] * LOG2E;
    float ssi0 = s_src[i0 + lm] + ba;
    float ssi1 = s_src[i0 + 16 + lm] + ba;
    const float* sd = s_dst + jb0 + lq * 8;
    const __hip_bfloat16* hb = hbB + ((size_t)(jh * NJT) * 8) * 512 + lane * 8;

    floatx4 acc0[8] = {}, acc1[8] = {};
    floatx4 accd0 = {}, accd1 = {};
    const short8 ones = { 0x3F80, 0x3F80, 0x3F80, 0x3F80, 0x3F80, 0x3F80, 0x3F80, 0x3F80 };

#pragma unroll
    for (int t = 0; t < NJT; t++) {
        // adj slices for both rowgroups: 8 ints each, 16B-aligned, nt (no L2 alloc)
        const uintx4* a0p = (const uintx4*)(arow0 + t * 32);
        const uintx4* a1p = (const uintx4*)(arow1 + t * 32);
        uintx4 m00 = __builtin_nontemporal_load(a0p);
        uintx4 m01 = __builtin_nontemporal_load(a0p + 1);
        uintx4 m10 = __builtin_nontemporal_load(a1p);
        uintx4 m11 = __builtin_nontemporal_load(a1p + 1);
        float4 cd0 = *(const float4*)(sd + t * 32);
        float4 cd1 = *(const float4*)(sd + t * 32 + 4);
        short8 af0 = make_pfrag(m00, m01, ssi0, cd0, cd1, &accd0, ones);
        short8 af1 = make_pfrag(m10, m11, ssi1, cd0, cd1, &accd1, ones);

        const __hip_bfloat16* hbt = hb + (size_t)t * 8 * 512;
#pragma unroll
        for (int f = 0; f < 8; f++) {
            short8 bf = *(const short8*)(hbt + f * 512);
            acc0[f] = __builtin_amdgcn_mfma_f32_16x16x32_bf16(af0, bf, acc0[f], 0, 0, 0);
            acc1[f] = __builtin_amdgcn_mfma_f32_16x16x32_bf16(af1, bf, acc1[f], 0, 0, 0);
        }
    }

    // epilogue: C/D layout col(dim-part)=lm, row=lq*4+r. nt stores: num is only
    // consumed by gat_combine (64 MB, from HBM regardless) -- keep L2 for hbB.
    float* nb = num + ((size_t)jh * NN + i0) * DOUT;
#pragma unroll
    for (int f = 0; f < 8; f++)
#pragma unroll
        for (int r = 0; r < 4; r++) {
            __builtin_nontemporal_store(acc0[f][r],
                &nb[(size_t)(lq * 4 + r) * DOUT + f * 16 + lm]);
            __builtin_nontemporal_store(acc1[f][r],
                &nb[(size_t)(16 + lq * 4 + r) * DOUT + f * 16 + lm]);
        }
    if (lm == 0) {
#pragma unroll
        for (int r = 0; r < 4; r++) {
            lpart[(size_t)jh * NN + i0 + lq * 4 + r] = accd0[r];
            lpart[(size_t)jh * NN + i0 + 16 + lq * 4 + r] = accd1[r];
        }
    }
}

// ---------------- kernel 3: combine partials, divide ----------------
__global__ void gat_combine(const float* __restrict__ num, const float* __restrict__ lpart,
                            float* __restrict__ out, int jsplit) {
    int gid = blockIdx.x * blockDim.x + threadIdx.x;  // 262144 threads, one float4 each
    int idx = gid * 4;
    int i = idx >> 7;
    float den = 0.f;
    for (int s = 0; s < jsplit; s++) den += lpart[(size_t)s * NN + i];
    float inv = 1.0f / den;
    floatx4 o = {0.f, 0.f, 0.f, 0.f};
    for (int s = 0; s < jsplit; s++) {
        floatx4 n = __builtin_nontemporal_load(
            (const floatx4*)&num[(size_t)s * NN * DOUT + idx]);
        o += n;
    }
    o *= inv;
    *(floatx4*)&out[idx] = o;
}

extern "C" void kernel_launch(void* const* d_in, const int* in_sizes, int n_in,
                              void* d_out, int out_size, void* d_ws, size_t ws_size,
                              hipStream_t stream) {
    const float* x  = (const float*)d_in[0];
    const int* adj  = (const int*)d_in[1];
    const float* W  = (const float*)d_in[2];
    const float* bW = (const float*)d_in[3];
    const float* a1 = (const float*)d_in[4];
    const float* a2 = (const float*)d_in[5];
    const float* ba = (const float*)d_in[6];
    float* out = (float*)d_out;

    char* ws = (char*)d_ws;
    __hip_bfloat16* hbB  = (__hip_bfloat16*)ws;                    // 2 MB   frag-tile layout
    __hip_bfloat16* WT   = (__hip_bfloat16*)(ws + 2097152);        // 64 KB
    float* s_src         = (float*)(ws + 2162688);                 // 32 KB (pre-scaled by log2e)
    float* s_dst         = (float*)(ws + 2195456);                 // 32 KB (pre-scaled by log2e)
    float* lpart         = (float*)(ws + 2228224);                 // 512 KB [<=16][8192]
    float* num           = (float*)(ws + 2752512);                 // jsplit*4 MB

    int jsplit = (ws_size >= 2752512 + (size_t)16 * NN * DOUT * 4) ? 16 : 8;

    prep_wt<<<128, 256, 0, stream>>>(W, WT);
    gat_h<<<256, 256, 0, stream>>>(x, WT, bW, a1, a2, hbB, s_src, s_dst);
    if (jsplit == 16)
        gat_attn<16><<<1024, 256, 0, stream>>>(adj, s_src, s_dst, ba, hbB, num, lpart);
    else
        gat_attn<32><<<512, 256, 0, stream>>>(adj, s_src, s_dst, ba, hbB, num, lpart);
    gat_combine<<<1024, 256, 0, stream>>>(num, lpart, out, jsplit);
}

// Round 2
// 462.879 us; speedup vs baseline: 1.0061x; 1.0061x over previous
//
#include <hip/hip_runtime.h>
#include <hip/hip_bf16.h>

// GAT layer, N=8192, DIN=256, DOUT=128.
// h = x@W+bW; e_ij = leaky_relu(s_src[i]+s_dst[j]+ba); p = adj ? exp(e) : 0
// (no max-subtraction: |e| <= ~10 unmasked, fp32-safe). out_i = (sum_j p_ij h_j)/(sum_j p_ij).
//
// R9: R8's fusion of build_mask into gat_attn regressed (440->466) because
// (a) nt adj loads defeated the L2 line reuse between the paired dwordx4
// reads of each 128B row-span (~2x HBM traffic, ~900cy latency each), and
// (b) the masks were consumed immediately after the load with only ~3
// waves/SIMD to hide the miss. Fix: plain cached adj loads + explicit
// depth-2 register pipeline (pm[2][4], fully unrolled t-loop so all
// indices are compile-time -- no scratch). num stores stay non-temporal
// (write-only stream, consumed from HBM by gat_combine anyway).

#define NN 8192
#define DIN 256
#define DOUT 128
#define LOG2E 1.4426950408889634f

typedef __attribute__((ext_vector_type(8))) short short8;   // 8 bf16 = 4 VGPRs (MFMA A/B frag)
typedef __attribute__((ext_vector_type(4))) float floatx4;  // MFMA C/D frag
typedef __attribute__((ext_vector_type(4))) unsigned int uintx4;

// ---------------- kernel 0: W [256][128] fp32 -> WT [128][256] bf16 ----------------
__global__ void prep_wt(const float* __restrict__ W, __hip_bfloat16* __restrict__ WT) {
    int e = blockIdx.x * blockDim.x + threadIdx.x;
    if (e < DIN * DOUT) {
        int k = e >> 7;
        int d = e & 127;
        WT[d * DIN + k] = __float2bfloat16(W[e]);
    }
}

// ---------------- kernel 1: h = x@W + bW (MFMA), fused s_src/s_dst; h -> hbB frag-tile layout ----------------
// hbB flat index for h-element (row i, dim d):
//   g=i>>5, k=i&31, f=d>>4, n=d&15 -> g*4096 + f*512 + (k>>3)*128 + n*8 + (k&7)
__global__ __launch_bounds__(256, 4) void gat_h(
    const float* __restrict__ x, const __hip_bfloat16* __restrict__ WT,
    const float* __restrict__ bW, const float* __restrict__ a1, const float* __restrict__ a2,
    __hip_bfloat16* __restrict__ hbB, float* __restrict__ s_src, float* __restrict__ s_dst) {
    int tid = threadIdx.x;
    int w = tid >> 6, lane = tid & 63;
    int lm = lane & 15, lq = lane >> 4;
    int i0 = blockIdx.x * 32;
    int r0 = (w >> 1) * 16;
    int c0 = (w & 1) * 64;

    __shared__ float s1s[32], s2s[32];
    if (tid < 32) { s1s[tid] = 0.f; s2s[tid] = 0.f; }
    __syncthreads();

    floatx4 acc[4] = {};
#pragma unroll
    for (int kk = 0; kk < DIN; kk += 32) {
        const float4* xp = (const float4*)&x[(size_t)(i0 + r0 + lm) * DIN + kk + lq * 8];
        float4 xa = xp[0], xb = xp[1];
        union { short8 v; __hip_bfloat16 h[8]; } af;
        af.h[0] = __float2bfloat16(xa.x); af.h[1] = __float2bfloat16(xa.y);
        af.h[2] = __float2bfloat16(xa.z); af.h[3] = __float2bfloat16(xa.w);
        af.h[4] = __float2bfloat16(xb.x); af.h[5] = __float2bfloat16(xb.y);
        af.h[6] = __float2bfloat16(xb.z); af.h[7] = __float2bfloat16(xb.w);
#pragma unroll
        for (int t = 0; t < 4; t++) {
            int d = c0 + 16 * t + lm;
            short8 bf = *(const short8*)&WT[(size_t)d * DIN + kk + lq * 8];
            acc[t] = __builtin_amdgcn_mfma_f32_16x16x32_bf16(af.v, bf, acc[t], 0, 0, 0);
        }
    }
    float s1[4] = {0.f, 0.f, 0.f, 0.f}, s2[4] = {0.f, 0.f, 0.f, 0.f};
#pragma unroll
    for (int t = 0; t < 4; t++) {
        int d = c0 + 16 * t + lm;
        int f = (c0 >> 4) + t;
        float A1 = a1[d], A2 = a2[d], B = bW[d];
#pragma unroll
        for (int r = 0; r < 4; r++) {
            int k = r0 + lq * 4 + r;
            float h = acc[t][r] + B;
            hbB[(size_t)blockIdx.x * 4096 + f * 512 + (k >> 3) * 128 + lm * 8 + (k & 7)] =
                __float2bfloat16(h);
            s1[r] += h * A1;
            s2[r] += h * A2;
        }
    }
#pragma unroll
    for (int r = 0; r < 4; r++) {
        for (int m = 1; m < 16; m <<= 1) {
            s1[r] += __shfl_xor(s1[r], m, 64);
            s2[r] += __shfl_xor(s2[r], m, 64);
        }
    }
    if (lm == 0) {
#pragma unroll
        for (int r = 0; r < 4; r++) {
            int row = r0 + lq * 4 + r;
            atomicAdd(&s1s[row], s1[r]);
            atomicAdd(&s2s[row], s2[r]);
        }
    }
    __syncthreads();
    if (tid < 32) {
        s_src[i0 + tid] = s1s[tid] * LOG2E;   // pre-scale: exp(e) = exp2(e*log2e)
        s_dst[i0 + tid] = s2s[tid] * LOG2E;
    }
}

// adj values are int 0/1; m!=0 <=> edge present.
__device__ inline short8 make_pfrag(uintx4 m0, uintx4 m1, float ssi, float4 cd0, float4 cd1,
                                    floatx4* accd, const short8 ones) {
    float p[8];
    float e;
    e = ssi + cd0.x; e = fmaxf(e, 0.01f * e); p[0] = m0.x ? __builtin_amdgcn_exp2f(e) : 0.f;
    e = ssi + cd0.y; e = fmaxf(e, 0.01f * e); p[1] = m0.y ? __builtin_amdgcn_exp2f(e) : 0.f;
    e = ssi + cd0.z; e = fmaxf(e, 0.01f * e); p[2] = m0.z ? __builtin_amdgcn_exp2f(e) : 0.f;
    e = ssi + cd0.w; e = fmaxf(e, 0.01f * e); p[3] = m0.w ? __builtin_amdgcn_exp2f(e) : 0.f;
    e = ssi + cd1.x; e = fmaxf(e, 0.01f * e); p[4] = m1.x ? __builtin_amdgcn_exp2f(e) : 0.f;
    e = ssi + cd1.y; e = fmaxf(e, 0.01f * e); p[5] = m1.y ? __builtin_amdgcn_exp2f(e) : 0.f;
    e = ssi + cd1.z; e = fmaxf(e, 0.01f * e); p[6] = m1.z ? __builtin_amdgcn_exp2f(e) : 0.f;
    e = ssi + cd1.w; e = fmaxf(e, 0.01f * e); p[7] = m1.w ? __builtin_amdgcn_exp2f(e) : 0.f;
    union { short8 v; __hip_bfloat162 q[4]; } af;
    af.q[0] = __float22bfloat162_rn(make_float2(p[0], p[1]));
    af.q[1] = __float22bfloat162_rn(make_float2(p[2], p[3]));
    af.q[2] = __float22bfloat162_rn(make_float2(p[4], p[5]));
    af.q[3] = __float22bfloat162_rn(make_float2(p[6], p[7]));
    *accd = __builtin_amdgcn_mfma_f32_16x16x32_bf16(af.v, ones, *accd, 0, 0, 0);
    return af.v;
}

// ---------------- kernel 2: fused mask + masked softmax-weighted GEMM, 32 rows/wave ----------------
// grid = 64 row-blocks (128 rows) x JSPLIT. Wave w: rows i0=ib*128+w*32 .. +31
// as two A-frag row-groups sharing each B-frag; all 128 dims.
// Lane (lm,lq) of rowgroup rg reads adj[i0+rg*16+lm, jb0+t*32+lq*8 .. +7]
// directly -- same j's as its cd0/cd1 s_dst slice. Masks are prefetched two
// t-iterations ahead into pm[2][4] (loop fully unrolled => static indices).
template <int NJT>
__global__ __launch_bounds__(256, 3) void gat_attn(
    const int* __restrict__ adj, const float* __restrict__ s_src,
    const float* __restrict__ s_dst, const float* __restrict__ ba_p,
    const __hip_bfloat16* __restrict__ hbB,
    float* __restrict__ num, float* __restrict__ lpart) {
    int tid = threadIdx.x;
    int w = tid >> 6, lane = tid & 63;
    int lm = lane & 15, lq = lane >> 4;
    int b = blockIdx.x;
    int ib = b & 63;
    int jh = b >> 6;
    int i0 = ib * 128 + w * 32;
    int jb0 = jh * (NJT * 32);

    const int* arow0 = adj + (size_t)(i0 + lm) * NN + jb0 + lq * 8;
    const int* arow1 = arow0 + (size_t)16 * NN;

    float ba = ba_p[0] * LOG2E;
    float ssi0 = s_src[i0 + lm] + ba;
    float ssi1 = s_src[i0 + 16 + lm] + ba;
    const float* sd = s_dst + jb0 + lq * 8;
    const __hip_bfloat16* hb = hbB + ((size_t)(jh * NJT) * 8) * 512 + lane * 8;

    floatx4 acc0[8] = {}, acc1[8] = {};
    floatx4 accd0 = {}, accd1 = {};
    const short8 ones = { 0x3F80, 0x3F80, 0x3F80, 0x3F80, 0x3F80, 0x3F80, 0x3F80, 0x3F80 };

    // depth-2 mask pipeline: pm[t&1] holds masks for iteration t
    uintx4 pm[2][4];
    {
        const uintx4* a0p = (const uintx4*)(arow0);
        const uintx4* a1p = (const uintx4*)(arow1);
        pm[0][0] = a0p[0]; pm[0][1] = a0p[1];
        pm[0][2] = a1p[0]; pm[0][3] = a1p[1];
        const uintx4* b0p = (const uintx4*)(arow0 + 32);
        const uintx4* b1p = (const uintx4*)(arow1 + 32);
        pm[1][0] = b0p[0]; pm[1][1] = b0p[1];
        pm[1][2] = b1p[0]; pm[1][3] = b1p[1];
    }

#pragma unroll
    for (int t = 0; t < NJT; t++) {
        uintx4 m00 = pm[t & 1][0], m01 = pm[t & 1][1];
        uintx4 m10 = pm[t & 1][2], m11 = pm[t & 1][3];
        if (t + 2 < NJT) {
            const uintx4* a0p = (const uintx4*)(arow0 + (t + 2) * 32);
            const uintx4* a1p = (const uintx4*)(arow1 + (t + 2) * 32);
            pm[t & 1][0] = a0p[0]; pm[t & 1][1] = a0p[1];
            pm[t & 1][2] = a1p[0]; pm[t & 1][3] = a1p[1];
        }
        float4 cd0 = *(const float4*)(sd + t * 32);
        float4 cd1 = *(const float4*)(sd + t * 32 + 4);
        short8 af0 = make_pfrag(m00, m01, ssi0, cd0, cd1, &accd0, ones);
        short8 af1 = make_pfrag(m10, m11, ssi1, cd0, cd1, &accd1, ones);

        const __hip_bfloat16* hbt = hb + (size_t)t * 8 * 512;
#pragma unroll
        for (int f = 0; f < 8; f++) {
            short8 bf = *(const short8*)(hbt + f * 512);
            acc0[f] = __builtin_amdgcn_mfma_f32_16x16x32_bf16(af0, bf, acc0[f], 0, 0, 0);
            acc1[f] = __builtin_amdgcn_mfma_f32_16x16x32_bf16(af1, bf, acc1[f], 0, 0, 0);
        }
    }

    // epilogue: C/D layout col(dim-part)=lm, row=lq*4+r. nt stores: num is only
    // consumed by gat_combine (64 MB, from HBM regardless) -- keep L2 for hbB.
    float* nb = num + ((size_t)jh * NN + i0) * DOUT;
#pragma unroll
    for (int f = 0; f < 8; f++)
#pragma unroll
        for (int r = 0; r < 4; r++) {
            __builtin_nontemporal_store(acc0[f][r],
                &nb[(size_t)(lq * 4 + r) * DOUT + f * 16 + lm]);
            __builtin_nontemporal_store(acc1[f][r],
                &nb[(size_t)(16 + lq * 4 + r) * DOUT + f * 16 + lm]);
        }
    if (lm == 0) {
#pragma unroll
        for (int r = 0; r < 4; r++) {
            lpart[(size_t)jh * NN + i0 + lq * 4 + r] = accd0[r];
            lpart[(size_t)jh * NN + i0 + 16 + lq * 4 + r] = accd1[r];
        }
    }
}

// ---------------- kernel 3: combine partials, divide ----------------
__global__ void gat_combine(const float* __restrict__ num, const float* __restrict__ lpart,
                            float* __restrict__ out, int jsplit) {
    int gid = blockIdx.x * blockDim.x + threadIdx.x;  // 262144 threads, one float4 each
    int idx = gid * 4;
    int i = idx >> 7;
    float den = 0.f;
    for (int s = 0; s < jsplit; s++) den += lpart[(size_t)s * NN + i];
    float inv = 1.0f / den;
    floatx4 o = {0.f, 0.f, 0.f, 0.f};
    for (int s = 0; s < jsplit; s++) {
        floatx4 n = __builtin_nontemporal_load(
            (const floatx4*)&num[(size_t)s * NN * DOUT + idx]);
        o += n;
    }
    o *= inv;
    *(floatx4*)&out[idx] = o;
}

extern "C" void kernel_launch(void* const* d_in, const int* in_sizes, int n_in,
                              void* d_out, int out_size, void* d_ws, size_t ws_size,
                              hipStream_t stream) {
    const float* x  = (const float*)d_in[0];
    const int* adj  = (const int*)d_in[1];
    const float* W  = (const float*)d_in[2];
    const float* bW = (const float*)d_in[3];
    const float* a1 = (const float*)d_in[4];
    const float* a2 = (const float*)d_in[5];
    const float* ba = (const float*)d_in[6];
    float* out = (float*)d_out;

    char* ws = (char*)d_ws;
    __hip_bfloat16* hbB  = (__hip_bfloat16*)ws;                    // 2 MB   frag-tile layout
    __hip_bfloat16* WT   = (__hip_bfloat16*)(ws + 2097152);        // 64 KB
    float* s_src         = (float*)(ws + 2162688);                 // 32 KB (pre-scaled by log2e)
    float* s_dst         = (float*)(ws + 2195456);                 // 32 KB (pre-scaled by log2e)
    float* lpart         = (float*)(ws + 2228224);                 // 512 KB [<=16][8192]
    float* num           = (float*)(ws + 2752512);                 // jsplit*4 MB

    int jsplit = (ws_size >= 2752512 + (size_t)16 * NN * DOUT * 4) ? 16 : 8;

    prep_wt<<<128, 256, 0, stream>>>(W, WT);
    gat_h<<<256, 256, 0, stream>>>(x, WT, bW, a1, a2, hbB, s_src, s_dst);
    if (jsplit == 16)
        gat_attn<16><<<1024, 256, 0, stream>>>(adj, s_src, s_dst, ba, hbB, num, lpart);
    else
        gat_attn<32><<<512, 256, 0, stream>>>(adj, s_src, s_dst, ba, hbB, num, lpart);
    gat_combine<<<1024, 256, 0, stream>>>(num, lpart, out, jsplit);
}

// Round 3
// 432.707 us; speedup vs baseline: 1.0763x; 1.0697x over previous
//
#include <hip/hip_runtime.h>
#include <hip/hip_bf16.h>

// GAT layer, N=8192, DIN=256, DOUT=128.
// h = x@W+bW; e_ij = leaky_relu(s_src[i]+s_dst[j]+ba); p = adj ? exp(e) : 0
// (no max-subtraction: |e| <= ~10 unmasked, fp32-safe). out_i = (sum_j p_ij h_j)/(sum_j p_ij).
//
// R10: occupancy fix. R9 counters: MfmaUtil 4.4 / VALU 9.9 / HBM 17% /
// Occupancy 23.7% -- latency-bound with ~2 waves/SIMD. Cause: 72 VGPR
// + 64 AGPR accumulators = 136 arch regs -> 3 blocks/CU resident, while
// grid=1024 needs 4/CU -> a half-duration straggler round at 1 block/CU
// (avg (12+4)/2 = 8 waves/CU = 25%, matches counter). Fix: drop the R9
// pm prefetch buffers (16 VGPRs, measured no-op) and declare
// launch_bounds(256,4) so each wave fits 128 regs -> all 1024 blocks
// co-resident (grid == 256 CUs x 4 exactly), one full round, no tail,
// 2x latency hiding. Mask-load latency then hides under 4-wave TLP.

#define NN 8192
#define DIN 256
#define DOUT 128
#define LOG2E 1.4426950408889634f

typedef __attribute__((ext_vector_type(8))) short short8;   // 8 bf16 = 4 VGPRs (MFMA A/B frag)
typedef __attribute__((ext_vector_type(4))) float floatx4;  // MFMA C/D frag
typedef __attribute__((ext_vector_type(4))) unsigned int uintx4;

// ---------------- kernel 0: W [256][128] fp32 -> WT [128][256] bf16 ----------------
__global__ void prep_wt(const float* __restrict__ W, __hip_bfloat16* __restrict__ WT) {
    int e = blockIdx.x * blockDim.x + threadIdx.x;
    if (e < DIN * DOUT) {
        int k = e >> 7;
        int d = e & 127;
        WT[d * DIN + k] = __float2bfloat16(W[e]);
    }
}

// ---------------- kernel 1: h = x@W + bW (MFMA), fused s_src/s_dst; h -> hbB frag-tile layout ----------------
// hbB flat index for h-element (row i, dim d):
//   g=i>>5, k=i&31, f=d>>4, n=d&15 -> g*4096 + f*512 + (k>>3)*128 + n*8 + (k&7)
__global__ __launch_bounds__(256, 4) void gat_h(
    const float* __restrict__ x, const __hip_bfloat16* __restrict__ WT,
    const float* __restrict__ bW, const float* __restrict__ a1, const float* __restrict__ a2,
    __hip_bfloat16* __restrict__ hbB, float* __restrict__ s_src, float* __restrict__ s_dst) {
    int tid = threadIdx.x;
    int w = tid >> 6, lane = tid & 63;
    int lm = lane & 15, lq = lane >> 4;
    int i0 = blockIdx.x * 32;
    int r0 = (w >> 1) * 16;
    int c0 = (w & 1) * 64;

    __shared__ float s1s[32], s2s[32];
    if (tid < 32) { s1s[tid] = 0.f; s2s[tid] = 0.f; }
    __syncthreads();

    floatx4 acc[4] = {};
#pragma unroll
    for (int kk = 0; kk < DIN; kk += 32) {
        const float4* xp = (const float4*)&x[(size_t)(i0 + r0 + lm) * DIN + kk + lq * 8];
        float4 xa = xp[0], xb = xp[1];
        union { short8 v; __hip_bfloat16 h[8]; } af;
        af.h[0] = __float2bfloat16(xa.x); af.h[1] = __float2bfloat16(xa.y);
        af.h[2] = __float2bfloat16(xa.z); af.h[3] = __float2bfloat16(xa.w);
        af.h[4] = __float2bfloat16(xb.x); af.h[5] = __float2bfloat16(xb.y);
        af.h[6] = __float2bfloat16(xb.z); af.h[7] = __float2bfloat16(xb.w);
#pragma unroll
        for (int t = 0; t < 4; t++) {
            int d = c0 + 16 * t + lm;
            short8 bf = *(const short8*)&WT[(size_t)d * DIN + kk + lq * 8];
            acc[t] = __builtin_amdgcn_mfma_f32_16x16x32_bf16(af.v, bf, acc[t], 0, 0, 0);
        }
    }
    float s1[4] = {0.f, 0.f, 0.f, 0.f}, s2[4] = {0.f, 0.f, 0.f, 0.f};
#pragma unroll
    for (int t = 0; t < 4; t++) {
        int d = c0 + 16 * t + lm;
        int f = (c0 >> 4) + t;
        float A1 = a1[d], A2 = a2[d], B = bW[d];
#pragma unroll
        for (int r = 0; r < 4; r++) {
            int k = r0 + lq * 4 + r;
            float h = acc[t][r] + B;
            hbB[(size_t)blockIdx.x * 4096 + f * 512 + (k >> 3) * 128 + lm * 8 + (k & 7)] =
                __float2bfloat16(h);
            s1[r] += h * A1;
            s2[r] += h * A2;
        }
    }
#pragma unroll
    for (int r = 0; r < 4; r++) {
        for (int m = 1; m < 16; m <<= 1) {
            s1[r] += __shfl_xor(s1[r], m, 64);
            s2[r] += __shfl_xor(s2[r], m, 64);
        }
    }
    if (lm == 0) {
#pragma unroll
        for (int r = 0; r < 4; r++) {
            int row = r0 + lq * 4 + r;
            atomicAdd(&s1s[row], s1[r]);
            atomicAdd(&s2s[row], s2[r]);
        }
    }
    __syncthreads();
    if (tid < 32) {
        s_src[i0 + tid] = s1s[tid] * LOG2E;   // pre-scale: exp(e) = exp2(e*log2e)
        s_dst[i0 + tid] = s2s[tid] * LOG2E;
    }
}

// adj values are int 0/1; m!=0 <=> edge present.
__device__ inline short8 make_pfrag(uintx4 m0, uintx4 m1, float ssi, float4 cd0, float4 cd1,
                                    floatx4* accd, const short8 ones) {
    float p[8];
    float e;
    e = ssi + cd0.x; e = fmaxf(e, 0.01f * e); p[0] = m0.x ? __builtin_amdgcn_exp2f(e) : 0.f;
    e = ssi + cd0.y; e = fmaxf(e, 0.01f * e); p[1] = m0.y ? __builtin_amdgcn_exp2f(e) : 0.f;
    e = ssi + cd0.z; e = fmaxf(e, 0.01f * e); p[2] = m0.z ? __builtin_amdgcn_exp2f(e) : 0.f;
    e = ssi + cd0.w; e = fmaxf(e, 0.01f * e); p[3] = m0.w ? __builtin_amdgcn_exp2f(e) : 0.f;
    e = ssi + cd1.x; e = fmaxf(e, 0.01f * e); p[4] = m1.x ? __builtin_amdgcn_exp2f(e) : 0.f;
    e = ssi + cd1.y; e = fmaxf(e, 0.01f * e); p[5] = m1.y ? __builtin_amdgcn_exp2f(e) : 0.f;
    e = ssi + cd1.z; e = fmaxf(e, 0.01f * e); p[6] = m1.z ? __builtin_amdgcn_exp2f(e) : 0.f;
    e = ssi + cd1.w; e = fmaxf(e, 0.01f * e); p[7] = m1.w ? __builtin_amdgcn_exp2f(e) : 0.f;
    union { short8 v; __hip_bfloat162 q[4]; } af;
    af.q[0] = __float22bfloat162_rn(make_float2(p[0], p[1]));
    af.q[1] = __float22bfloat162_rn(make_float2(p[2], p[3]));
    af.q[2] = __float22bfloat162_rn(make_float2(p[4], p[5]));
    af.q[3] = __float22bfloat162_rn(make_float2(p[6], p[7]));
    *accd = __builtin_amdgcn_mfma_f32_16x16x32_bf16(af.v, ones, *accd, 0, 0, 0);
    return af.v;
}

// ---------------- kernel 2: fused mask + masked softmax-weighted GEMM, 32 rows/wave ----------------
// grid = 64 row-blocks (128 rows) x JSPLIT. Wave w: rows i0=ib*128+w*32 .. +31
// as two A-frag row-groups sharing each B-frag; all 128 dims.
// Lane (lm,lq) of rowgroup rg reads adj[i0+rg*16+lm, jb0+t*32+lq*8 .. +7]
// directly (cached; the paired dwordx4 of each 128B row-line hit L1/L2).
template <int NJT>
__global__ __launch_bounds__(256, 4) void gat_attn(
    const int* __restrict__ adj, const float* __restrict__ s_src,
    const float* __restrict__ s_dst, const float* __restrict__ ba_p,
    const __hip_bfloat16* __restrict__ hbB,
    float* __restrict__ num, float* __restrict__ lpart) {
    int tid = threadIdx.x;
    int w = tid >> 6, lane = tid & 63;
    int lm = lane & 15, lq = lane >> 4;
    int b = blockIdx.x;
    int ib = b & 63;
    int jh = b >> 6;
    int i0 = ib * 128 + w * 32;
    int jb0 = jh * (NJT * 32);

    const int* arow0 = adj + (size_t)(i0 + lm) * NN + jb0 + lq * 8;
    const int* arow1 = arow0 + (size_t)16 * NN;

    float ba = ba_p[0] * LOG2E;
    float ssi0 = s_src[i0 + lm] + ba;
    float ssi1 = s_src[i0 + 16 + lm] + ba;
    const float* sd = s_dst + jb0 + lq * 8;
    const __hip_bfloat16* hb = hbB + ((size_t)(jh * NJT) * 8) * 512 + lane * 8;

    floatx4 acc0[8] = {}, acc1[8] = {};
    floatx4 accd0 = {}, accd1 = {};
    const short8 ones = { 0x3F80, 0x3F80, 0x3F80, 0x3F80, 0x3F80, 0x3F80, 0x3F80, 0x3F80 };

#pragma unroll
    for (int t = 0; t < NJT; t++) {
        const uintx4* a0p = (const uintx4*)(arow0 + t * 32);
        const uintx4* a1p = (const uintx4*)(arow1 + t * 32);
        uintx4 m00 = a0p[0], m01 = a0p[1];
        uintx4 m10 = a1p[0], m11 = a1p[1];
        float4 cd0 = *(const float4*)(sd + t * 32);
        float4 cd1 = *(const float4*)(sd + t * 32 + 4);
        short8 af0 = make_pfrag(m00, m01, ssi0, cd0, cd1, &accd0, ones);
        short8 af1 = make_pfrag(m10, m11, ssi1, cd0, cd1, &accd1, ones);

        const __hip_bfloat16* hbt = hb + (size_t)t * 8 * 512;
#pragma unroll
        for (int f = 0; f < 8; f++) {
            short8 bf = *(const short8*)(hbt + f * 512);
            acc0[f] = __builtin_amdgcn_mfma_f32_16x16x32_bf16(af0, bf, acc0[f], 0, 0, 0);
            acc1[f] = __builtin_amdgcn_mfma_f32_16x16x32_bf16(af1, bf, acc1[f], 0, 0, 0);
        }
    }

    // epilogue: C/D layout col(dim-part)=lm, row=lq*4+r. nt stores: num is only
    // consumed by gat_combine (64 MB, from HBM regardless) -- keep L2 for hbB.
    float* nb = num + ((size_t)jh * NN + i0) * DOUT;
#pragma unroll
    for (int f = 0; f < 8; f++)
#pragma unroll
        for (int r = 0; r < 4; r++) {
            __builtin_nontemporal_store(acc0[f][r],
                &nb[(size_t)(lq * 4 + r) * DOUT + f * 16 + lm]);
            __builtin_nontemporal_store(acc1[f][r],
                &nb[(size_t)(16 + lq * 4 + r) * DOUT + f * 16 + lm]);
        }
    if (lm == 0) {
#pragma unroll
        for (int r = 0; r < 4; r++) {
            lpart[(size_t)jh * NN + i0 + lq * 4 + r] = accd0[r];
            lpart[(size_t)jh * NN + i0 + 16 + lq * 4 + r] = accd1[r];
        }
    }
}

// ---------------- kernel 3: combine partials, divide ----------------
__global__ void gat_combine(const float* __restrict__ num, const float* __restrict__ lpart,
                            float* __restrict__ out, int jsplit) {
    int gid = blockIdx.x * blockDim.x + threadIdx.x;  // 262144 threads, one float4 each
    int idx = gid * 4;
    int i = idx >> 7;
    float den = 0.f;
    for (int s = 0; s < jsplit; s++) den += lpart[(size_t)s * NN + i];
    float inv = 1.0f / den;
    floatx4 o = {0.f, 0.f, 0.f, 0.f};
    for (int s = 0; s < jsplit; s++) {
        floatx4 n = __builtin_nontemporal_load(
            (const floatx4*)&num[(size_t)s * NN * DOUT + idx]);
        o += n;
    }
    o *= inv;
    *(floatx4*)&out[idx] = o;
}

extern "C" void kernel_launch(void* const* d_in, const int* in_sizes, int n_in,
                              void* d_out, int out_size, void* d_ws, size_t ws_size,
                              hipStream_t stream) {
    const float* x  = (const float*)d_in[0];
    const int* adj  = (const int*)d_in[1];
    const float* W  = (const float*)d_in[2];
    const float* bW = (const float*)d_in[3];
    const float* a1 = (const float*)d_in[4];
    const float* a2 = (const float*)d_in[5];
    const float* ba = (const float*)d_in[6];
    float* out = (float*)d_out;

    char* ws = (char*)d_ws;
    __hip_bfloat16* hbB  = (__hip_bfloat16*)ws;                    // 2 MB   frag-tile layout
    __hip_bfloat16* WT   = (__hip_bfloat16*)(ws + 2097152);        // 64 KB
    float* s_src         = (float*)(ws + 2162688);                 // 32 KB (pre-scaled by log2e)
    float* s_dst         = (float*)(ws + 2195456);                 // 32 KB (pre-scaled by log2e)
    float* lpart         = (float*)(ws + 2228224);                 // 512 KB [<=16][8192]
    float* num           = (float*)(ws + 2752512);                 // jsplit*4 MB

    int jsplit = (ws_size >= 2752512 + (size_t)16 * NN * DOUT * 4) ? 16 : 8;

    prep_wt<<<128, 256, 0, stream>>>(W, WT);
    gat_h<<<256, 256, 0, stream>>>(x, WT, bW, a1, a2, hbB, s_src, s_dst);
    if (jsplit == 16)
        gat_attn<16><<<1024, 256, 0, stream>>>(adj, s_src, s_dst, ba, hbB, num, lpart);
    else
        gat_attn<32><<<512, 256, 0, stream>>>(adj, s_src, s_dst, ba, hbB, num, lpart);
    gat_combine<<<1024, 256, 0, stream>>>(num, lpart, out, jsplit);
}